// Round 3
// baseline (163.755 us; speedup 1.0000x reference)
//
#include <hip/hip_runtime.h>
#include <hip/hip_bf16.h>
#include <math.h>

#define N_NODES 20000
#define N_EDGES 200000
#define D_IN 32
#define D_H 32
#define D_OUT 8
#define E_DIM 16
#define NK 17
#define W2S_SHORTS (NK * 2 * 64 * 8)        // 17408 bf16 (w2+b2 fragments)
#define PREP_SHORTS (W2S_SHORTS + 64 * 8)   // + w1/b1 fragment = 17920 shorts = 35840 B

typedef __attribute__((ext_vector_type(8))) short bf16x8;
typedef __attribute__((ext_vector_type(4))) float f32x4;

__device__ __forceinline__ float elu_f(float v) { return v > 0.f ? v : expm1f(v); }
__device__ __forceinline__ short f2bf(float f) {
    union { __hip_bfloat16 h; short s; } u;
    u.h = __float2bfloat16(f);
    return u.s;
}
__device__ __forceinline__ float bf2f(__hip_bfloat16 h) { return __bfloat162float(h); }

// ---------------- zero degree array (replaces rocclr fill) ----------------
__global__ __launch_bounds__(256)
void zero_deg_kernel(int* __restrict__ deg) {
    int i = blockIdx.x * 256 + threadIdx.x;
    if (i < N_NODES) deg[i] = 0;
}

// ---------------- degree histogram ----------------
__global__ __launch_bounds__(256)
void deg_kernel(const int* __restrict__ dst, int* __restrict__ deg) {
    int e = blockIdx.x * 256 + threadIdx.x;
    if (e < N_EDGES) atomicAdd(&deg[dst[e]], 1);
}

// ---------------- exclusive scan, single block ----------------
__global__ __launch_bounds__(1024)
void scan_kernel(const int* __restrict__ deg, int* __restrict__ rowptr, int* __restrict__ cursor) {
    __shared__ int part[1024];
    const int t = threadIdx.x;
    const int base = t * 20;
    int loc[20];
    int sum = 0;
    #pragma unroll
    for (int j = 0; j < 20; ++j) {
        int idx = base + j;
        int v = (idx < N_NODES) ? deg[idx] : 0;
        loc[j] = v;
        sum += v;
    }
    part[t] = sum;
    __syncthreads();
    for (int off = 1; off < 1024; off <<= 1) {
        int v = (t >= off) ? part[t - off] : 0;
        __syncthreads();
        part[t] += v;
        __syncthreads();
    }
    int run = part[t] - sum;
    #pragma unroll
    for (int j = 0; j < 20; ++j) {
        int idx = base + j;
        if (idx < N_NODES) { rowptr[idx] = run; cursor[idx] = run; run += loc[j]; }
    }
    if (t == 0) rowptr[N_NODES] = N_EDGES;
}

// ---------------- CSR fill ----------------
__global__ __launch_bounds__(256)
void fill_kernel(const int* __restrict__ dst, int* __restrict__ cursor, int* __restrict__ edge_order) {
    int e = blockIdx.x * 256 + threadIdx.x;
    if (e < N_EDGES) {
        int pos = atomicAdd(&cursor[dst[e]], 1);
        edge_order[pos] = e;
    }
}

// ---------------- prep: swizzled bf16 fragments for BOTH layers ----------------
// W2'' frags: buf[((kk*2+tile)*64+l)*8+j] = W2''[kk*32 + (l>>4)*8+j][tile*16 + (l&15)]
//   W2''[k*32+i][o] = w2[k][i*32+o]  (k<16);  W2''[512+i][o] = b2[i*32+o]
// w1 frag (A-layout B): buf[W2S + l*8+j] = w1[k][n] (k<16), b1[n] (k==16), 0 else;
//   k=(l>>4)*8+j, n=l&15
__global__ __launch_bounds__(256)
void prep_kernel(const float* __restrict__ w2_0, const float* __restrict__ b2_0,
                 const float* __restrict__ w1_0, const float* __restrict__ b1_0,
                 const float* __restrict__ w2_1, const float* __restrict__ b2_1,
                 const float* __restrict__ w1_1, const float* __restrict__ b1_1,
                 short* __restrict__ buf)
{
    int idx = blockIdx.x * 256 + threadIdx.x;
    if (idx >= 2 * PREP_SHORTS) return;
    int layer = idx >= PREP_SHORTS ? 1 : 0;
    int r = idx - layer * PREP_SHORTS;
    const float* w2 = layer ? w2_1 : w2_0;
    const float* b2 = layer ? b2_1 : b2_0;
    const float* w1 = layer ? w1_1 : w1_0;
    const float* b1 = layer ? b1_1 : b1_0;
    float v;
    if (r < W2S_SHORTS) {
        int j = r & 7, l = (r >> 3) & 63, tile = (r >> 9) & 1, kk = r >> 10;
        int ii = (l >> 4) * 8 + j;
        int o = tile * 16 + (l & 15);
        v = (kk < 16) ? w2[kk * 1024 + ii * 32 + o] : b2[ii * 32 + o];
    } else {
        int q = r - W2S_SHORTS;
        int j = q & 7, l = q >> 3;
        int k = (l >> 4) * 8 + j, n = l & 15;
        v = (k < 16) ? w1[k * 16 + n] : (k == 16 ? b1[n] : 0.f);
    }
    buf[idx] = f2bf(v);
}

// ---------------- fused edge kernel ----------------
// Per wave: 16 edges. h = elu(ea@w1+b1) via 1 MFMA; msg = f @ W2'' via 34 MFMA
// with A = W2''-fragment (LDS), B = x-fragment (regs, constant over K-steps),
// h-contraction in VALU (4 FMA per tile). D: lane holds msg[edge=lane&15][o=kg*4+r (+16)].
__global__ __launch_bounds__(256)
void edge_mfma_kernel(const float* __restrict__ xin,
                      const float* __restrict__ edge_attr,
                      const int* __restrict__ src,
                      const short* __restrict__ prep,
                      __hip_bfloat16* __restrict__ msg)
{
    __shared__ __align__(16) short w2s[PREP_SHORTS];   // 35840 B
    __shared__ __align__(16) float h_s[4][16][20];     // 5120 B (pad 20: conflict-free)

    const int t = threadIdx.x;
    for (int i = t; i < PREP_SHORTS / 8; i += 256)
        ((int4*)w2s)[i] = ((const int4*)prep)[i];

    const int lane = t & 63;
    const int wave = t >> 6;
    const int eloc = lane & 15;
    const int kg = lane >> 4;
    const int e = blockIdx.x * 64 + wave * 16 + eloc;

    // issue gathers early
    const int sn = src[e];
    const float4 x0 = *(const float4*)(xin + (size_t)sn * 32 + kg * 8);
    const float4 x1 = *(const float4*)(xin + (size_t)sn * 32 + kg * 8 + 4);

    // edge-attr A-fragment: A[m=eloc][k=kg*8+j]; k=16 -> 1.0 (bias), k>16 -> 0
    bf16x8 af = {0, 0, 0, 0, 0, 0, 0, 0};
    if (kg < 2) {
        const float4 a0 = *(const float4*)(edge_attr + (size_t)e * E_DIM + kg * 8);
        const float4 a1 = *(const float4*)(edge_attr + (size_t)e * E_DIM + kg * 8 + 4);
        af[0] = f2bf(a0.x); af[1] = f2bf(a0.y); af[2] = f2bf(a0.z); af[3] = f2bf(a0.w);
        af[4] = f2bf(a1.x); af[5] = f2bf(a1.y); af[6] = f2bf(a1.z); af[7] = f2bf(a1.w);
    } else if (kg == 2) {
        af[0] = f2bf(1.0f);
    }

    __syncthreads();  // staging complete

    const f32x4 zero4 = {0.f, 0.f, 0.f, 0.f};

    // edge MLP: one MFMA; lane gets h[edge=kg*4+r][k_out=eloc]
    {
        bf16x8 w1f = *(const bf16x8*)&w2s[W2S_SHORTS + lane * 8];
        f32x4 hd = __builtin_amdgcn_mfma_f32_16x16x32_bf16(af, w1f, zero4, 0, 0, 0);
        #pragma unroll
        for (int r = 0; r < 4; ++r)
            h_s[wave][kg * 4 + r][eloc] = elu_f(hd[r]);
    }

    // x B-fragment: B[k=kg*8+j][n=eloc] = x[e][kg*8+j]
    bf16x8 xb;
    xb[0] = f2bf(x0.x); xb[1] = f2bf(x0.y); xb[2] = f2bf(x0.z); xb[3] = f2bf(x0.w);
    xb[4] = f2bf(x1.x); xb[5] = f2bf(x1.y); xb[6] = f2bf(x1.z); xb[7] = f2bf(x1.w);

    __syncthreads();  // h_s ready

    // this lane's edge h-row (16 f32, 4x ds_read_b128)
    float hr[16];
    *(f32x4*)&hr[0]  = *(const f32x4*)&h_s[wave][eloc][0];
    *(f32x4*)&hr[4]  = *(const f32x4*)&h_s[wave][eloc][4];
    *(f32x4*)&hr[8]  = *(const f32x4*)&h_s[wave][eloc][8];
    *(f32x4*)&hr[12] = *(const f32x4*)&h_s[wave][eloc][12];

    float m0[4] = {0, 0, 0, 0}, m1[4] = {0, 0, 0, 0};
    #pragma unroll
    for (int kk = 0; kk < 16; ++kk) {
        bf16x8 a0 = *(const bf16x8*)&w2s[(kk * 2 + 0) * 512 + lane * 8];
        bf16x8 a1 = *(const bf16x8*)&w2s[(kk * 2 + 1) * 512 + lane * 8];
        f32x4 d0 = __builtin_amdgcn_mfma_f32_16x16x32_bf16(a0, xb, zero4, 0, 0, 0);
        f32x4 d1 = __builtin_amdgcn_mfma_f32_16x16x32_bf16(a1, xb, zero4, 0, 0, 0);
        const float hk = hr[kk];
        #pragma unroll
        for (int r = 0; r < 4; ++r) { m0[r] += hk * d0[r]; m1[r] += hk * d1[r]; }
    }
    {   // kk = 16: b2 rows, f = x directly (h == 1)
        bf16x8 a0 = *(const bf16x8*)&w2s[(16 * 2 + 0) * 512 + lane * 8];
        bf16x8 a1 = *(const bf16x8*)&w2s[(16 * 2 + 1) * 512 + lane * 8];
        f32x4 d0 = __builtin_amdgcn_mfma_f32_16x16x32_bf16(a0, xb, zero4, 0, 0, 0);
        f32x4 d1 = __builtin_amdgcn_mfma_f32_16x16x32_bf16(a1, xb, zero4, 0, 0, 0);
        #pragma unroll
        for (int r = 0; r < 4; ++r) { m0[r] += d0[r]; m1[r] += d1[r]; }
    }

    // store: lane owns msg[e][kg*4 .. kg*4+3] and msg[e][16+kg*4 .. 16+kg*4+3]
    short* mp = (short*)(msg + (size_t)e * D_H);
    short q0[4] = { f2bf(m0[0]), f2bf(m0[1]), f2bf(m0[2]), f2bf(m0[3]) };
    short q1[4] = { f2bf(m1[0]), f2bf(m1[1]), f2bf(m1[2]), f2bf(m1[3]) };
    *(int2*)(mp + kg * 4)      = *(int2*)q0;
    *(int2*)(mp + 16 + kg * 4) = *(int2*)q1;
}

// ---------------- aggregation (wave per node) + root GEMM + ELU (+ fused classifier) ----------------
template<bool LAST>
__global__ __launch_bounds__(256)
void agg_kernel(const float* __restrict__ xin,
                const __hip_bfloat16* __restrict__ msg,
                const int* __restrict__ rowptr,
                const int* __restrict__ edge_order,
                const float* __restrict__ root,
                const float* __restrict__ bias,
                const float* __restrict__ cls_w,
                const float* __restrict__ cls_b,
                float* __restrict__ hout,
                float* __restrict__ out)
{
    __shared__ float root_s[32 * 32];
    __shared__ float bias_s[32];
    __shared__ float h2_s[4][33];
    const int t = threadIdx.x;
    for (int i = t; i < 1024; i += 256) root_s[i] = root[i];
    if (t < 32) bias_s[t] = bias[t];
    __syncthreads();

    const int lane = t & 63;
    const int wave = t >> 6;
    const int o = lane & 31;
    const int half = lane >> 5;
    const int n = blockIdx.x * 4 + wave;

    const int start = rowptr[n];
    const int end   = rowptr[n + 1];
    float s = 0.f;
    for (int j = start + half; j < end; j += 2)
        s += bf2f(msg[(size_t)edge_order[j] * D_H + o]);
    s += __shfl_xor(s, 32);

    float acc = s * (1.f / fmaxf((float)(end - start), 1.f)) + bias_s[o];
    const float xv = xin[(size_t)n * 32 + o];
    #pragma unroll
    for (int i = 0; i < 32; ++i)
        acc += __shfl(xv, half * 32 + i) * root_s[i * 32 + o];
    acc = elu_f(acc);

    if (!LAST) {
        if (half == 0) hout[(size_t)n * 32 + o] = acc;
    } else {
        if (half == 0) h2_s[wave][o] = acc;
        __syncthreads();
        if (t < 32) {
            const int nn = t >> 3, j = t & 7;
            float a = cls_b[j];
            #pragma unroll
            for (int i = 0; i < 32; ++i) a += h2_s[nn][i] * cls_w[i * 8 + j];
            out[(size_t)(blockIdx.x * 4 + nn) * D_OUT + j] = a;
        }
    }
}

extern "C" void kernel_launch(void* const* d_in, const int* in_sizes, int n_in,
                              void* d_out, int out_size, void* d_ws, size_t ws_size,
                              hipStream_t stream)
{
    const float* x          = (const float*)d_in[0];
    const float* edge_attr  = (const float*)d_in[1];
    const int*   edge_index = (const int*)d_in[2];
    const float* w1_0 = (const float*)d_in[3];
    const float* b1_0 = (const float*)d_in[4];
    const float* w2_0 = (const float*)d_in[5];
    const float* b2_0 = (const float*)d_in[6];
    const float* root_0 = (const float*)d_in[7];
    const float* bias_0 = (const float*)d_in[8];
    const float* w1_1 = (const float*)d_in[9];
    const float* b1_1 = (const float*)d_in[10];
    const float* w2_1 = (const float*)d_in[11];
    const float* b2_1 = (const float*)d_in[12];
    const float* root_1 = (const float*)d_in[13];
    const float* bias_1 = (const float*)d_in[14];
    const float* cls_w = (const float*)d_in[15];
    const float* cls_b = (const float*)d_in[16];

    const int* src = edge_index;
    const int* dst = edge_index + N_EDGES;

    char* ws = (char*)d_ws;
    int* deg_i      = (int*)ws;                        // 20000
    int* rowptr     = deg_i + N_NODES;                 // 20001
    int* cursor     = rowptr + N_NODES + 1;            // 20000
    int* edge_order = cursor + N_NODES;                // 200000
    size_t off = ((size_t)(N_NODES * 3 + 1 + N_EDGES) * 4 + 15) & ~(size_t)15;
    short* prep = (short*)(ws + off);                  // 2 layers x 17920 shorts
    off = (off + (size_t)2 * PREP_SHORTS * 2 + 15) & ~(size_t)15;
    __hip_bfloat16* msg = (__hip_bfloat16*)(ws + off); // E*32 bf16 = 12.8 MB
    off = (off + (size_t)N_EDGES * D_H * 2 + 15) & ~(size_t)15;
    float* h = (float*)(ws + off);                     // N*32 f32

    const int EB = (N_EDGES + 255) / 256;   // 782
    const int ZB = (N_NODES + 255) / 256;   // 79
    const int PB = (2 * PREP_SHORTS) / 256; // 140

    // CSR build
    zero_deg_kernel<<<ZB, 256, 0, stream>>>(deg_i);
    deg_kernel<<<EB, 256, 0, stream>>>(dst, deg_i);
    scan_kernel<<<1, 1024, 0, stream>>>(deg_i, rowptr, cursor);
    fill_kernel<<<EB, 256, 0, stream>>>(dst, cursor, edge_order);

    // both layers' weight fragments
    prep_kernel<<<PB, 256, 0, stream>>>(w2_0, b2_0, w1_0, b1_0,
                                        w2_1, b2_1, w1_1, b1_1, prep);

    // layer 0
    edge_mfma_kernel<<<N_EDGES / 64, 256, 0, stream>>>(x, edge_attr, src, prep, msg);
    agg_kernel<false><<<N_NODES / 4, 256, 0, stream>>>(x, msg, rowptr, edge_order,
                                                       root_0, bias_0, cls_w, cls_b,
                                                       h, (float*)d_out);
    // layer 1 (+ fused classifier)
    edge_mfma_kernel<<<N_EDGES / 64, 256, 0, stream>>>(h, edge_attr, src,
                                                       prep + PREP_SHORTS, msg);
    agg_kernel<true><<<N_NODES / 4, 256, 0, stream>>>(h, msg, rowptr, edge_order,
                                                      root_1, bias_1, cls_w, cls_b,
                                                      nullptr, (float*)d_out);
}